// Round 13
// baseline (723.646 us; speedup 1.0000x reference)
//
#include <hip/hip_runtime.h>
#include <hip/hip_bf16.h>

#define NSEQ 100000
#define NLAB 64
#define ECON 1600000
#define D 128
#define BN_EPS 1e-5f

#define NB 196        // buckets (dst and src)
#define BW 512        // nodes per bucket
#define BCAP 10240    // record capacity per bucket
#define EPB 4096      // edges per block in k_binA
#define NPART 32      // rotating partial buffers for stats flushes
#define RPB 4096      // rows per block in k_lab_scatter

typedef unsigned int uint32;
typedef unsigned short ushort;
typedef __attribute__((ext_vector_type(8))) short bf16x8;
typedef __attribute__((ext_vector_type(4))) float f32x4;

// ---------------- helpers ----------------
__device__ __forceinline__ void atomAddF(float* p, float v) {
  unsafeAtomicAdd(p, v);  // native global_atomic_add_f32
}
__device__ __forceinline__ float blo(uint32 u) {
  union { uint32 u; float f; } c; c.u = u << 16; return c.f;
}
__device__ __forceinline__ float bhi(uint32 u) {
  union { uint32 u; float f; } c; c.u = u & 0xFFFF0000u; return c.f;
}
__device__ __forceinline__ unsigned short f2b(float f) {
  __hip_bfloat16 h = __float2bfloat16(f);   // RNE
  union { __hip_bfloat16 h; unsigned short s; } c; c.h = h; return c.s;
}

// ---------------- label histogram ----------------
__global__ __launch_bounds__(256) void k_label_hist(const int* __restrict__ lab, int* cnt) {
  __shared__ int h[NLAB];
  if (threadIdx.x < NLAB) h[threadIdx.x] = 0;
  __syncthreads();
  for (int i = blockIdx.x * 256 + threadIdx.x; i < NSEQ; i += gridDim.x * 256)
    atomicAdd(&h[lab[i]], 1);
  __syncthreads();
  if (threadIdx.x < NLAB) atomicAdd(&cnt[threadIdx.x], h[threadIdx.x]);
}

// ---------------- CSR build pass A: dual-key LDS-staged bucket sort -----------
__global__ __launch_bounds__(256) void k_binA(const int* __restrict__ src,
                                              const int* __restrict__ dst,
                                              int* bucket_cnt, int* sbucket_cnt,
                                              uint32* __restrict__ bpair,
                                              ushort* __restrict__ spair) {
  __shared__ uint32 recD[EPB];          // 16 KB dst-keyed records
  __shared__ ushort recS[EPB];          //  8 KB src-keyed records
  __shared__ unsigned char bidD[EPB];   //  4 KB
  __shared__ unsigned char bidS[EPB];   //  4 KB
  __shared__ int histD[NB], histS[NB], loffD[NB], loffS[NB], gbD[NB], gbS[NB];
  int t = threadIdx.x;
  for (int i = t; i < NB; i += 256) { histD[i] = 0; histS[i] = 0; }
  __syncthreads();
  int e0 = blockIdx.x * EPB;
  int e1 = min(e0 + EPB, ECON);
  for (int e = e0 + t; e < e1; e += 256) {
    atomicAdd(&histD[dst[e] >> 9], 1);
    atomicAdd(&histS[src[e] >> 9], 1);
  }
  __syncthreads();
  if (t == 0) { int a = 0; for (int i = 0; i < NB; ++i) { loffD[i] = a; a += histD[i]; } }
  if (t == 1) { int a = 0; for (int i = 0; i < NB; ++i) { loffS[i] = a; a += histS[i]; } }
  __syncthreads();
  for (int i = t; i < NB; i += 256) {
    int c = histD[i]; gbD[i] = c ? atomicAdd(&bucket_cnt[i], c) : 0; histD[i] = 0;
    int cs = histS[i]; gbS[i] = cs ? atomicAdd(&sbucket_cnt[i], cs) : 0; histS[i] = 0;
  }
  __syncthreads();
  for (int e = e0 + t; e < e1; e += 256) {   // 2nd read: L2-hot
    int s = src[e], d = dst[e];
    int b = d >> 9;
    int p = loffD[b] + atomicAdd(&histD[b], 1);
    recD[p] = (uint32)s | ((uint32)(d & (BW - 1)) << 17);
    bidD[p] = (unsigned char)b;
    int bs = s >> 9;
    int q = loffS[bs] + atomicAdd(&histS[bs], 1);
    recS[q] = (ushort)(s & (BW - 1));
    bidS[q] = (unsigned char)bs;
  }
  __syncthreads();
  int n = e1 - e0;
  for (int i = t; i < n; i += 256) {         // coalesced flushes
    int b = bidD[i];
    bpair[(size_t)b * BCAP + gbD[b] + (i - loffD[b])] = recD[i];
  }
  for (int i = t; i < n; i += 256) {
    int b = bidS[i];
    spair[(size_t)b * BCAP + gbS[b] + (i - loffS[b])] = recS[i];
  }
}

// ---------------- scans: buckets, labels (+ dinv_cnt) -------------------------
__global__ __launch_bounds__(256) void k_bscan(const int* __restrict__ bucket_cnt,
                                               int* __restrict__ bbase,
                                               const int* __restrict__ cnt_lab,
                                               float* __restrict__ dinv_cnt,
                                               int* __restrict__ lab_base,
                                               int* __restrict__ lab_cursor) {
  int t = threadIdx.x;
  if (t == 0) {
    int acc = 0;
    for (int i = 0; i < NB; ++i) { bbase[i] = acc; acc += bucket_cnt[i]; }
    bbase[NB] = acc;
  }
  if (t == 1) {
    int acc = 0;
    for (int i = 0; i < NLAB; ++i) {
      lab_base[i] = acc; lab_cursor[i] = acc; acc += cnt_lab[i];
    }
    lab_base[NLAB] = acc;
  }
  if (t < NLAB) { int c = cnt_lab[t]; dinv_cnt[t] = c > 0 ? rsqrtf((float)c) : 0.f; }
}

// ---------------- CSR build pass B (dst): per-bucket scatter + off/dinv_in ----
__global__ __launch_bounds__(256) void k_binB(const uint32* __restrict__ bpair,
                                              const int* __restrict__ bucket_cnt,
                                              const int* __restrict__ bbase,
                                              int* __restrict__ off,
                                              float* __restrict__ dinv_in,
                                              int* __restrict__ esrc) {
  __shared__ int deg[BW];
  __shared__ int loff[BW];
  __shared__ int cursor[BW];
  __shared__ int wsum[4];
  int b = blockIdx.x;
  int t = threadIdx.x;
  int cnt = bucket_cnt[b];
  int gbase = bbase[b];
  const uint32* bp = &bpair[(size_t)b * BCAP];
  deg[t] = 0; deg[t + 256] = 0;
  cursor[t] = 0; cursor[t + 256] = 0;
  __syncthreads();
  for (int i = t; i < cnt; i += 256)
    atomicAdd(&deg[bp[i] >> 17], 1);
  __syncthreads();
  int d0 = deg[2 * t], d1 = deg[2 * t + 1];
  int ps = d0 + d1;
  int lane = t & 63, w = t >> 6;
  int v = ps;
  #pragma unroll
  for (int o = 1; o < 64; o <<= 1) { int n = __shfl_up(v, o); if (lane >= o) v += n; }
  if (lane == 63) wsum[w] = v;
  __syncthreads();
  int wbase = 0;
  for (int i = 0; i < w; ++i) wbase += wsum[i];
  int excl = wbase + v - ps;
  loff[2 * t] = excl;
  loff[2 * t + 1] = excl + d0;
  __syncthreads();
  #pragma unroll
  for (int k = 0; k < 2; ++k) {
    int j = t + k * 256;
    int node = b * BW + j;
    if (node < NSEQ) {
      int dg = deg[j];
      off[node] = gbase + loff[j];
      dinv_in[node] = dg > 0 ? rsqrtf((float)dg) : 0.f;
    }
  }
  if (b == NB - 1 && t == 0) off[NSEQ] = ECON;
  for (int i = t; i < cnt; i += 256) {
    uint32 pk = bp[i];
    int dl = pk >> 17;
    int p = gbase + loff[dl] + atomicAdd(&cursor[dl], 1);
    esrc[p] = (int)(pk & 0x1FFFF);
  }
}

// ---------------- CSR build pass B (src): out-degree -> dinv_out --------------
__global__ __launch_bounds__(256) void k_binBS(const ushort* __restrict__ spair,
                                               const int* __restrict__ sbucket_cnt,
                                               float* __restrict__ dinv_out) {
  __shared__ int deg[BW];
  int b = blockIdx.x, t = threadIdx.x;
  int cnt = sbucket_cnt[b];
  deg[t] = 0; deg[t + 256] = 0;
  __syncthreads();
  const ushort* sp = &spair[(size_t)b * BCAP];
  for (int i = t; i < cnt; i += 256) atomicAdd(&deg[sp[i]], 1);
  __syncthreads();
  #pragma unroll
  for (int k = 0; k < 2; ++k) {
    int j = t + k * 256;
    int node = b * BW + j;
    if (node < NSEQ) {
      int dg = deg[j];
      dinv_out[node] = dg > 0 ? rsqrtf((float)dg) : 0.f;
    }
  }
}

// ---------------- label counting sort: row indices grouped by label -----------
__global__ __launch_bounds__(256) void k_lab_scatter(const int* __restrict__ lab,
                                                     int* lab_cursor,
                                                     int* __restrict__ lab_sorted) {
  __shared__ int hist[NLAB], base[NLAB];
  int t = threadIdx.x;
  if (t < NLAB) hist[t] = 0;
  __syncthreads();
  int r0 = blockIdx.x * RPB, r1 = min(r0 + RPB, NSEQ);
  for (int r = r0 + t; r < r1; r += 256) atomicAdd(&hist[lab[r]], 1);
  __syncthreads();
  if (t < NLAB) {
    int c = hist[t];
    base[t] = (c > 0) ? atomicAdd(&lab_cursor[t], c) : 0;
    hist[t] = 0;
  }
  __syncthreads();
  for (int r = r0 + t; r < r1; r += 256) {
    int l = lab[r];
    int p = base[l] + atomicAdd(&hist[l], 1);
    lab_sorted[p] = r;
  }
}

// ---------------- BN params: statsP -> a[], cc[] ------------------------------
__global__ __launch_bounds__(128) void k_bnparams(const float* __restrict__ statsP,
                                                  const float* __restrict__ g,
                                                  const float* __restrict__ beta,
                                                  float* __restrict__ aV,
                                                  float* __restrict__ ccV) {
  int c = threadIdx.x;   // 128
  float s = 0.f, q = 0.f;
  #pragma unroll
  for (int k = 0; k < NPART; ++k) {
    s += statsP[k * 256 + c];
    q += statsP[k * 256 + 128 + c];
  }
  const float invN = 1.f / (float)NSEQ;
  float m = s * invN;
  float a = rsqrtf(q * invN - m * m + BN_EPS) * g[c];
  aV[c] = a;
  ccV[c] = beta[c] - m * a;
}

// ---------------- label aggregation via sorted gather -------------------------
// AFFINE=1: source is pre-BN; output = a ⊙ Σpre + cnt*cc (BN folded in)
template <int AFFINE>
__global__ __launch_bounds__(256) void k_lab_agg(const uint32* __restrict__ xb,
                                                 const int* __restrict__ lab_sorted,
                                                 const int* __restrict__ lab_base,
                                                 const float* __restrict__ aV,
                                                 const float* __restrict__ ccV,
                                                 float* __restrict__ lab_agg) {
  __shared__ float accs[4][D];
  int t = threadIdx.x;
  int l = blockIdx.x >> 3, p = blockIdx.x & 7;
  int w = t >> 6, cp = t & 63;
  int i0 = lab_base[l], i1 = lab_base[l + 1];
  float ax = 0.f, ay = 0.f;
  for (int i = i0 + p * 4 + w; i < i1; i += 32) {
    int r = lab_sorted[i];
    uint32 u = xb[r * 64 + cp];
    ax += blo(u); ay += bhi(u);
  }
  accs[w][2 * cp] = ax;
  accs[w][2 * cp + 1] = ay;
  __syncthreads();
  if (w == 0) {
    float s0 = accs[0][2 * cp] + accs[1][2 * cp] + accs[2][2 * cp] + accs[3][2 * cp];
    float s1 = accs[0][2 * cp + 1] + accs[1][2 * cp + 1] + accs[2][2 * cp + 1] + accs[3][2 * cp + 1];
    if (AFFINE) {
      s0 *= aV[2 * cp];
      s1 *= aV[2 * cp + 1];
      if (p == 0) {
        float cnt = (float)(i1 - i0);
        s0 += cnt * ccV[2 * cp];
        s1 += cnt * ccV[2 * cp + 1];
      }
    }
    atomAddF(&lab_agg[l * D + 2 * cp], s0);
    atomAddF(&lab_agg[l * D + 2 * cp + 1], s1);
  }
}

// ---------------- fp32 -> bf16 cast (pure stream) ------------------------------
__global__ __launch_bounds__(256) void k_cast(const float* __restrict__ x,
                                              uint32* __restrict__ xb) {
  int i = blockIdx.x * 256 + threadIdx.x;     // float4 index
  if (i >= NSEQ * D / 4) return;
  float4 v = ((const float4*)x)[i];
  uint32 u0 = (uint32)f2b(v.x) | ((uint32)f2b(v.y) << 16);
  uint32 u1 = (uint32)f2b(v.z) | ((uint32)f2b(v.w) << 16);
  ((uint2*)xb)[i] = make_uint2(u0, u1);
}

// ---------------- weight prep: W (128x128 fp32, k-major) -> W^T bf16 ----------
__global__ __launch_bounds__(256) void k_prep_w(const float* __restrict__ W1,
                                                const float* __restrict__ W2,
                                                short* __restrict__ wT1,
                                                short* __restrict__ wT2) {
  int i = blockIdx.x * 256 + threadIdx.x;
  if (i < 16384) {
    int k = i >> 7, c = i & 127;
    wT1[c * 128 + k] = (short)f2b(W1[i]);
  } else if (i < 32768) {
    int j = i - 16384;
    int k = j >> 7, c = j & 127;
    wT2[c * 128 + k] = (short)f2b(W2[j]);
  }
}

// ---------------- small matmul: out[64][ncol] = op((A*rowscale) @ W + bias) ---
__global__ __launch_bounds__(256) void k_mm(
    const float* __restrict__ A, const float* __restrict__ rowscale,
    const float* __restrict__ W, const float* __restrict__ bias,
    float* __restrict__ out, int ncol, int relu) {
  __shared__ float sA[4 * D];
  int tid = threadIdx.x;
  int rows_pb = 256 / ncol;
  int row0 = blockIdx.x * rows_pb;
  int nload = rows_pb * D;
  for (int i = tid; i < nload; i += 256) {
    int r = row0 + (i >> 7);
    float s = rowscale ? rowscale[r] : 1.f;
    sA[i] = A[r * D + (i & 127)] * s;
  }
  __syncthreads();
  int j = tid & (ncol - 1);
  int r = tid / ncol;
  const float* a = &sA[r * D];
  const float* w = &W[j];
  float acc0 = 0.f, acc1 = 0.f, acc2 = 0.f, acc3 = 0.f;
  #pragma unroll 4
  for (int k = 0; k < D; k += 4) {
    acc0 = fmaf(a[k + 0], w[(k + 0) * ncol], acc0);
    acc1 = fmaf(a[k + 1], w[(k + 1) * ncol], acc1);
    acc2 = fmaf(a[k + 2], w[(k + 2) * ncol], acc2);
    acc3 = fmaf(a[k + 3], w[(k + 3) * ncol], acc3);
  }
  float s = (acc0 + acc1) + (acc2 + acc3);
  if (bias) s += bias[j];
  if (relu) s = fmaxf(s, 0.f);
  out[(row0 + r) * ncol + j] = s;
}

// ---------------- BN over 64 label rows ---------------------------------------
__global__ __launch_bounds__(256) void k_label_bn(
    const float* __restrict__ pre,
    const float* __restrict__ g, const float* __restrict__ beta,
    float* __restrict__ out, int ncol) {
  __shared__ float psum[256], psq[256];
  __shared__ float sa[128], sc[128];
  int tid = threadIdx.x;
  int ngrp = 256 / ncol;
  int grp = tid / ncol;
  int col = tid & (ncol - 1);
  float s = 0.f, q = 0.f;
  for (int r = grp; r < NLAB; r += ngrp) {
    float v = pre[r * ncol + col];
    s += v; q += v * v;
  }
  psum[tid] = s; psq[tid] = q;
  __syncthreads();
  if (tid < ncol) {
    float S = 0.f, Q = 0.f;
    for (int gi = 0; gi < ngrp; ++gi) { S += psum[gi * ncol + tid]; Q += psq[gi * ncol + tid]; }
    float m = S * (1.f / NLAB);
    float v = Q * (1.f / NLAB) - m * m;
    float a = rsqrtf(v + BN_EPS) * g[tid];
    sa[tid] = a; sc[tid] = beta[tid] - m * a;
  }
  __syncthreads();
  for (int i = tid; i < NLAB * ncol; i += 256) {
    int c = i & (ncol - 1);
    out[i] = pre[i] * sa[c] + sc[c];
  }
}

// ---------------- connected_to aggregation: XCD-pinned column slices ----------
// slice = blockIdx&7 (round-robin -> same XCD): 16 cols (8 uint32) of every row;
// per-XCD feature working set = 3.2 MB -> L2-resident.
// 8 lanes per dst row (1 uint32 each), 32 row-groups per block.
// AFFINE=1: source is pre-BN h1; BN folded in via a,cc and edge-weight sum.
template <int AFFINE>
__global__ __launch_bounds__(256) void k_con_agg_sl(
    const uint32* __restrict__ xb, const int* __restrict__ esrc,
    const int* __restrict__ off,
    const float* __restrict__ dinv_out, const float* __restrict__ dinv_in,
    const float* __restrict__ aV, const float* __restrict__ ccV,
    uint32* __restrict__ outb) {
  int slice = blockIdx.x & 7;
  int chunk = blockIdx.x >> 3;
  int g = threadIdx.x >> 3;            // 0..31 row group
  int j = threadIdx.x & 7;             // uint32 within slice
  int colu = slice * 8 + j;            // uint32 column (0..63)
  float a0 = 0.f, a1 = 0.f, c0 = 0.f, c1 = 0.f;
  if (AFFINE) {
    a0 = aV[2 * colu]; a1 = aV[2 * colu + 1];
    c0 = ccV[2 * colu]; c1 = ccV[2 * colu + 1];
  }
  int rowEnd = min(chunk * 256 + 256, NSEQ);
  for (int row = chunk * 256 + g; row < rowEnd; row += 32) {
    int e = off[row], e1 = off[row + 1];
    float ax = 0.f, ay = 0.f, sw = 0.f;
    for (; e + 1 < e1; e += 2) {       // 2-edge unroll for load ILP
      int s0 = esrc[e], s1 = esrc[e + 1];
      float w0 = dinv_out[s0], w1 = dinv_out[s1];
      uint32 u0 = xb[s0 * 64 + colu];
      uint32 u1 = xb[s1 * 64 + colu];
      ax += blo(u0) * w0 + blo(u1) * w1;
      ay += bhi(u0) * w0 + bhi(u1) * w1;
      if (AFFINE) sw += w0 + w1;
    }
    if (e < e1) {
      int s0 = esrc[e];
      float w0 = dinv_out[s0];
      uint32 u0 = xb[s0 * 64 + colu];
      ax += blo(u0) * w0;
      ay += bhi(u0) * w0;
      if (AFFINE) sw += w0;
    }
    float di = dinv_in[row];
    float rx, ry;
    if (AFFINE) {
      rx = di * fmaf(a0, ax, c0 * sw);
      ry = di * fmaf(a1, ay, c1 * sw);
    } else {
      rx = di * ax;
      ry = di * ay;
    }
    outb[row * 64 + colu] = (uint32)f2b(rx) | ((uint32)f2b(ry) << 16);
  }
}

// ---------------- MFMA GEMM + epilogue + BN partial stats ----------------------
template <int OUTBF>
__global__ __launch_bounds__(256) void k_gemm_mfma(
    const short* __restrict__ aggbf,    // NSEQ x 128 bf16
    const short* __restrict__ wT,       // 128(col) x 128(k) bf16
    const float* __restrict__ b_con,
    const float* __restrict__ y_inc,    // 64x128 fp32
    const float* __restrict__ b_inc,
    const float* __restrict__ dinv_cnt,
    const int* __restrict__ bel,
    float* __restrict__ outF,           // fp32 out (OUTBF=0)
    short* __restrict__ outB,           // bf16 out (OUTBF=1)
    float* __restrict__ statsP) {       // NPART x [sum 128][sumsq 128]
  __shared__ short sW[128 * 136];       // 272B row stride
  __shared__ float csum[D], csq[D];
  int t = threadIdx.x;
  {
    const uint4* src = (const uint4*)wT;   // 2048 uint4, 16 per row
    for (int i = t; i < 2048; i += 256) {
      int row = i >> 4, part = i & 15;
      *(uint4*)&sW[row * 136 + part * 8] = src[i];
    }
  }
  if (t < D) { csum[t] = 0.f; csq[t] = 0.f; }
  int w = t >> 6, l = t & 63;
  int lr = l & 15, lg = l >> 4;
  int row0 = blockIdx.x * 64 + w * 16;
  bf16x8 afrag[4];
  {
    int arow = min(row0 + lr, NSEQ - 1);
    const short* ab = aggbf + arow * 128 + lg * 8;
    #pragma unroll
    for (int kt = 0; kt < 4; ++kt)
      afrag[kt] = *(const bf16x8*)(ab + kt * 32);
  }
  __syncthreads();
  f32x4 acc[8];
  #pragma unroll
  for (int ct = 0; ct < 8; ++ct) {
    f32x4 a = {0.f, 0.f, 0.f, 0.f};
    const short* wb = &sW[(ct * 16 + lr) * 136 + lg * 8];
    #pragma unroll
    for (int kt = 0; kt < 4; ++kt) {
      bf16x8 bfr = *(const bf16x8*)(wb + kt * 32);
      a = __builtin_amdgcn_mfma_f32_16x16x32_bf16(afrag[kt], bfr, a, 0, 0, 0);
    }
    acc[ct] = a;
  }
  int belr[4]; float dcv[4]; int rowv[4];
  #pragma unroll
  for (int r = 0; r < 4; ++r) {
    int gr = row0 + lg * 4 + r;
    rowv[r] = gr;
    int cl = min(gr, NSEQ - 1);
    belr[r] = bel[cl];
    dcv[r] = dinv_cnt[belr[r]];
  }
  #pragma unroll
  for (int ct = 0; ct < 8; ++ct) {
    int col = ct * 16 + lr;
    float bc = b_con[col], bi = b_inc[col];
    float s = 0.f, q = 0.f;
    #pragma unroll
    for (int r = 0; r < 4; ++r) {
      if (rowv[r] < NSEQ) {
        float o = acc[ct][r] + bc + fmaf(dcv[r], y_inc[belr[r] * D + col], bi);
        o = fmaxf(0.5f * o, 0.f);
        if (OUTBF) outB[rowv[r] * D + col] = (short)f2b(o);
        else       outF[rowv[r] * D + col] = o;
        s += o; q += o * o;
      }
    }
    s += __shfl_xor(s, 16); s += __shfl_xor(s, 32);
    q += __shfl_xor(q, 16); q += __shfl_xor(q, 32);
    if (lg == 0) {
      atomicAdd(&csum[col], s);
      atomicAdd(&csq[col], q);
    }
  }
  __syncthreads();
  float* sp = statsP + (blockIdx.x & (NPART - 1)) * 256;
  if (t < D) {
    atomAddF(&sp[t], csum[t]);
    atomAddF(&sp[D + t], csq[t]);
  }
}

// ---------------- final BN apply (fp32 in place, precomputed params) ----------
__global__ __launch_bounds__(256) void k_bn_apply2(
    float* __restrict__ buf, const float* __restrict__ aV,
    const float* __restrict__ ccV) {
  int t = threadIdx.x;
  int w = t >> 6, cp = t & 63;
  float a0 = aV[2 * cp], a1 = aV[2 * cp + 1];
  float c0 = ccV[2 * cp], c1 = ccV[2 * cp + 1];
  for (int r = blockIdx.x * 4 + w; r < NSEQ; r += gridDim.x * 4) {
    float2 v = ((float2*)buf)[r * 64 + cp];
    v.x = fmaf(v.x, a0, c0);
    v.y = fmaf(v.y, a1, c1);
    ((float2*)buf)[r * 64 + cp] = v;
  }
}

// ---------------- launch ------------------------------------------------------
extern "C" void kernel_launch(void* const* d_in, const int* in_sizes, int n_in,
                              void* d_out, int out_size, void* d_ws, size_t ws_size,
                              hipStream_t stream) {
  const float* x_seq   = (const float*)d_in[0];
  const float* x_label = (const float*)d_in[1];
  const float* W1_bel  = (const float*)d_in[2];
  const float* b1_bel  = (const float*)d_in[3];
  const float* W1_inc  = (const float*)d_in[4];
  const float* b1_inc  = (const float*)d_in[5];
  const float* W1_con  = (const float*)d_in[6];
  const float* b1_con  = (const float*)d_in[7];
  const float* g1s     = (const float*)d_in[8];
  const float* beta1s  = (const float*)d_in[9];
  const float* g1l     = (const float*)d_in[10];
  const float* beta1l  = (const float*)d_in[11];
  const float* W2_bel  = (const float*)d_in[12];
  const float* b2_bel  = (const float*)d_in[13];
  const float* W2_inc  = (const float*)d_in[14];
  const float* b2_inc  = (const float*)d_in[15];
  const float* W2_con  = (const float*)d_in[16];
  const float* b2_con  = (const float*)d_in[17];
  const float* g2s     = (const float*)d_in[18];
  const float* beta2s  = (const float*)d_in[19];
  const float* g2l     = (const float*)d_in[20];
  const float* beta2l  = (const float*)d_in[21];
  const int* bel       = (const int*)d_in[22];
  const int* con_src   = (const int*)d_in[23];
  const int* con_dst   = (const int*)d_in[24];
  float* out = (float*)d_out;

  char* ws = (char*)d_ws;
  short*  aggbf    = (short*) (ws);                  // 25,600,000 B
  short*  h1pre    = (short*) (ws + 25600000);       // 25,600,000 B
  uint32* bpair    = (uint32*)(ws + 32000000);       //  8,028,160 B (dead after binB)
  ushort* spair    = (ushort*)(ws + 40028160);       //  4,014,080 B (dead after binBS)
  int*    esrc     = (int*)   (ws + 51200000);       //  6,400,000 B
  float*  dinv_out = (float*) (ws + 57600000);       //    400,000 B
  // ---- zeroed region start (134,144 B) ----
  int*    cnt_lab     = (int*)  (ws + 58000000);     //   1,024
  int*    bucket_cnt  = (int*)  (ws + 58001024);     //   1,024
  int*    sbucket_cnt = (int*)  (ws + 58002048);     //   1,024
  float*  statsP1     = (float*)(ws + 58003072);     //  32,768 (32 x 256 f32)
  float*  statsP2     = (float*)(ws + 58035840);     //  32,768
  float*  lab_agg1    = (float*)(ws + 58068608);     //  32,768
  float*  lab_agg2    = (float*)(ws + 58101376);     //  32,768
  // ---- zeroed region end (58,134,144) ----
  float*  dinv_in    = (float*)(ws + 58134144);      // 400,000
  float*  dinv_cnt   = (float*)(ws + 58534144);      //     256
  int*    bbase      = (int*)  (ws + 58534400);      //   1,024
  int*    off        = (int*)  (ws + 58535424);      // 400,128
  float*  y_inc1     = (float*)(ws + 58935552);      //  32,768
  float*  y_inc2     = (float*)(ws + 58968320);      //  32,768
  float*  h_l1       = (float*)(ws + 59001088);      //  32,768
  short*  wT1        = (short*)(ws + 59033856);      //  32,768
  short*  wT2        = (short*)(ws + 59066624);      //  32,768
  int*    lab_base   = (int*)  (ws + 59099392);      //   1,024 (65 used)
  int*    lab_cursor = (int*)  (ws + 59100416);      //   1,024
  int*    lab_sorted = (int*)  (ws + 59101440);      // 400,000
  float*  ab1        = (float*)(ws + 59501440);      //     512
  float*  cc1        = (float*)(ws + 59501952);      //     512
  float*  ab2        = (float*)(ws + 59502464);      //     512
  float*  cc2        = (float*)(ws + 59502976);      //     512
  // end: 59,503,488 B

  uint32* xb = (uint32*)out;           // bf16 x features, d_out[0..25.6MB)
  float* belp1 = (float*)ws;           // transient, overwritten by con_agg
  float* belp2 = (float*)ws;

  hipMemsetAsync(ws + 58000000, 0, 134144, stream);

  // CSR build (dual-key, atomic-free per edge) + label sort + prep
  k_label_hist <<<256, 256, 0, stream>>>(bel, cnt_lab);
  k_binA       <<<(ECON + EPB - 1) / EPB, 256, 0, stream>>>(con_src, con_dst,
                                                            bucket_cnt, sbucket_cnt,
                                                            bpair, spair);
  k_bscan      <<<1, 256, 0, stream>>>(bucket_cnt, bbase, cnt_lab, dinv_cnt,
                                       lab_base, lab_cursor);
  k_binB       <<<NB, 256, 0, stream>>>(bpair, bucket_cnt, bbase,
                                        off, dinv_in, esrc);
  k_binBS      <<<NB, 256, 0, stream>>>(spair, sbucket_cnt, dinv_out);
  k_lab_scatter<<<(NSEQ + RPB - 1) / RPB, 256, 0, stream>>>(bel, lab_cursor, lab_sorted);
  k_cast       <<<(NSEQ * D / 4 + 255) / 256, 256, 0, stream>>>(x_seq, xb);
  k_prep_w     <<<128, 256, 0, stream>>>(W1_con, W2_con, wT1, wT2);

  const int CON_GRID = 8 * ((NSEQ + 255) / 256);   // 8 slices x 391 chunks

  // ---- layer 1 ----
  k_lab_agg<0> <<<NLAB * 8, 256, 0, stream>>>(xb, lab_sorted, lab_base,
                                              nullptr, nullptr, lab_agg1);
  k_mm         <<<32, 256, 0, stream>>>(x_label, nullptr, W1_inc, nullptr, y_inc1, 128, 0);
  k_mm         <<<32, 256, 0, stream>>>(lab_agg1, dinv_cnt, W1_bel, b1_bel, belp1, 128, 1);
  k_label_bn   <<<1, 256, 0, stream>>>(belp1, g1l, beta1l, h_l1, 128);
  k_con_agg_sl<0><<<CON_GRID, 256, 0, stream>>>(xb, esrc, off, dinv_out, dinv_in,
                                                nullptr, nullptr, (uint32*)aggbf);
  k_gemm_mfma<1><<<(NSEQ + 63) / 64, 256, 0, stream>>>(
                   aggbf, wT1, b1_con, y_inc1, b1_inc, dinv_cnt, bel,
                   nullptr, h1pre, statsP1);
  k_bnparams   <<<1, 128, 0, stream>>>(statsP1, g1s, beta1s, ab1, cc1);

  // ---- layer 2 (BN folded into linear consumers) ----
  k_lab_agg<1> <<<NLAB * 8, 256, 0, stream>>>((const uint32*)h1pre, lab_sorted,
                                              lab_base, ab1, cc1, lab_agg2);
  k_mm         <<<32, 256, 0, stream>>>(h_l1, nullptr, W2_inc, nullptr, y_inc2, 128, 0);
  k_mm         <<<16, 256, 0, stream>>>(lab_agg2, dinv_cnt, W2_bel, b2_bel, belp2, 64, 1);
  k_label_bn   <<<1, 256, 0, stream>>>(belp2, g2l, beta2l, out + (size_t)NSEQ * D, 64);
  k_con_agg_sl<1><<<CON_GRID, 256, 0, stream>>>((const uint32*)h1pre, esrc, off,
                                                dinv_out, dinv_in, ab1, cc1,
                                                (uint32*)aggbf);
  k_gemm_mfma<0><<<(NSEQ + 63) / 64, 256, 0, stream>>>(
                   aggbf, wT2, b2_con, y_inc2, b2_inc, dinv_cnt, bel,
                   out, nullptr, statsP2);
  k_bnparams   <<<1, 128, 0, stream>>>(statsP2, g2s, beta2s, ab2, cc2);
  k_bn_apply2  <<<1024, 256, 0, stream>>>(out, ab2, cc2);
}

// Round 14
// 432.875 us; speedup vs baseline: 1.6717x; 1.6717x over previous
//
#include <hip/hip_runtime.h>
#include <hip/hip_bf16.h>

#define NSEQ 100000
#define NLAB 64
#define ECON 1600000
#define D 128
#define BN_EPS 1e-5f

#define NB 196        // buckets (dst and src)
#define BW 512        // nodes per bucket
#define BCAP 10240    // record capacity per bucket
#define EPB 4096      // edges per block in k_binA
#define NPART 32      // rotating partial buffers for stats flushes
#define RPB 4096      // rows per block in k_lab_scatter

typedef unsigned int uint32;
typedef unsigned short ushort;
typedef __attribute__((ext_vector_type(8))) short bf16x8;
typedef __attribute__((ext_vector_type(4))) float f32x4;

// ---------------- helpers ----------------
__device__ __forceinline__ void atomAddF(float* p, float v) {
  unsafeAtomicAdd(p, v);  // native global_atomic_add_f32
}
__device__ __forceinline__ float blo(uint32 u) {
  union { uint32 u; float f; } c; c.u = u << 16; return c.f;
}
__device__ __forceinline__ float bhi(uint32 u) {
  union { uint32 u; float f; } c; c.u = u & 0xFFFF0000u; return c.f;
}
__device__ __forceinline__ unsigned short f2b(float f) {
  __hip_bfloat16 h = __float2bfloat16(f);   // RNE
  union { __hip_bfloat16 h; unsigned short s; } c; c.h = h; return c.s;
}

// ---------------- label histogram ----------------
__global__ __launch_bounds__(256) void k_label_hist(const int* __restrict__ lab, int* cnt) {
  __shared__ int h[NLAB];
  if (threadIdx.x < NLAB) h[threadIdx.x] = 0;
  __syncthreads();
  for (int i = blockIdx.x * 256 + threadIdx.x; i < NSEQ; i += gridDim.x * 256)
    atomicAdd(&h[lab[i]], 1);
  __syncthreads();
  if (threadIdx.x < NLAB) atomicAdd(&cnt[threadIdx.x], h[threadIdx.x]);
}

// ---------------- CSR build pass A: dual-key LDS-staged bucket sort -----------
__global__ __launch_bounds__(256) void k_binA(const int* __restrict__ src,
                                              const int* __restrict__ dst,
                                              int* bucket_cnt, int* sbucket_cnt,
                                              uint32* __restrict__ bpair,
                                              ushort* __restrict__ spair) {
  __shared__ uint32 recD[EPB];          // 16 KB dst-keyed records
  __shared__ ushort recS[EPB];          //  8 KB src-keyed records
  __shared__ unsigned char bidD[EPB];   //  4 KB
  __shared__ unsigned char bidS[EPB];   //  4 KB
  __shared__ int histD[NB], histS[NB], loffD[NB], loffS[NB], gbD[NB], gbS[NB];
  int t = threadIdx.x;
  for (int i = t; i < NB; i += 256) { histD[i] = 0; histS[i] = 0; }
  __syncthreads();
  int e0 = blockIdx.x * EPB;
  int e1 = min(e0 + EPB, ECON);
  for (int e = e0 + t; e < e1; e += 256) {
    atomicAdd(&histD[dst[e] >> 9], 1);
    atomicAdd(&histS[src[e] >> 9], 1);
  }
  __syncthreads();
  if (t == 0) { int a = 0; for (int i = 0; i < NB; ++i) { loffD[i] = a; a += histD[i]; } }
  if (t == 1) { int a = 0; for (int i = 0; i < NB; ++i) { loffS[i] = a; a += histS[i]; } }
  __syncthreads();
  for (int i = t; i < NB; i += 256) {
    int c = histD[i]; gbD[i] = c ? atomicAdd(&bucket_cnt[i], c) : 0; histD[i] = 0;
    int cs = histS[i]; gbS[i] = cs ? atomicAdd(&sbucket_cnt[i], cs) : 0; histS[i] = 0;
  }
  __syncthreads();
  for (int e = e0 + t; e < e1; e += 256) {   // 2nd read: L2-hot
    int s = src[e], d = dst[e];
    int b = d >> 9;
    int p = loffD[b] + atomicAdd(&histD[b], 1);
    recD[p] = (uint32)s | ((uint32)(d & (BW - 1)) << 17);
    bidD[p] = (unsigned char)b;
    int bs = s >> 9;
    int q = loffS[bs] + atomicAdd(&histS[bs], 1);
    recS[q] = (ushort)(s & (BW - 1));
    bidS[q] = (unsigned char)bs;
  }
  __syncthreads();
  int n = e1 - e0;
  for (int i = t; i < n; i += 256) {         // coalesced flushes
    int b = bidD[i];
    bpair[(size_t)b * BCAP + gbD[b] + (i - loffD[b])] = recD[i];
  }
  for (int i = t; i < n; i += 256) {
    int b = bidS[i];
    spair[(size_t)b * BCAP + gbS[b] + (i - loffS[b])] = recS[i];
  }
}

// ---------------- scans: buckets, labels (+ dinv_cnt) -------------------------
__global__ __launch_bounds__(256) void k_bscan(const int* __restrict__ bucket_cnt,
                                               int* __restrict__ bbase,
                                               const int* __restrict__ cnt_lab,
                                               float* __restrict__ dinv_cnt,
                                               int* __restrict__ lab_base,
                                               int* __restrict__ lab_cursor) {
  int t = threadIdx.x;
  if (t == 0) {
    int acc = 0;
    for (int i = 0; i < NB; ++i) { bbase[i] = acc; acc += bucket_cnt[i]; }
    bbase[NB] = acc;
  }
  if (t == 1) {
    int acc = 0;
    for (int i = 0; i < NLAB; ++i) {
      lab_base[i] = acc; lab_cursor[i] = acc; acc += cnt_lab[i];
    }
    lab_base[NLAB] = acc;
  }
  if (t < NLAB) { int c = cnt_lab[t]; dinv_cnt[t] = c > 0 ? rsqrtf((float)c) : 0.f; }
}

// ---------------- CSR build pass B (dst): per-bucket scatter + off/dinv_in ----
__global__ __launch_bounds__(256) void k_binB(const uint32* __restrict__ bpair,
                                              const int* __restrict__ bucket_cnt,
                                              const int* __restrict__ bbase,
                                              int* __restrict__ off,
                                              float* __restrict__ dinv_in,
                                              int* __restrict__ esrc) {
  __shared__ int deg[BW];
  __shared__ int loff[BW];
  __shared__ int cursor[BW];
  __shared__ int wsum[4];
  int b = blockIdx.x;
  int t = threadIdx.x;
  int cnt = bucket_cnt[b];
  int gbase = bbase[b];
  const uint32* bp = &bpair[(size_t)b * BCAP];
  deg[t] = 0; deg[t + 256] = 0;
  cursor[t] = 0; cursor[t + 256] = 0;
  __syncthreads();
  for (int i = t; i < cnt; i += 256)
    atomicAdd(&deg[bp[i] >> 17], 1);
  __syncthreads();
  int d0 = deg[2 * t], d1 = deg[2 * t + 1];
  int ps = d0 + d1;
  int lane = t & 63, w = t >> 6;
  int v = ps;
  #pragma unroll
  for (int o = 1; o < 64; o <<= 1) { int n = __shfl_up(v, o); if (lane >= o) v += n; }
  if (lane == 63) wsum[w] = v;
  __syncthreads();
  int wbase = 0;
  for (int i = 0; i < w; ++i) wbase += wsum[i];
  int excl = wbase + v - ps;
  loff[2 * t] = excl;
  loff[2 * t + 1] = excl + d0;
  __syncthreads();
  #pragma unroll
  for (int k = 0; k < 2; ++k) {
    int j = t + k * 256;
    int node = b * BW + j;
    if (node < NSEQ) {
      int dg = deg[j];
      off[node] = gbase + loff[j];
      dinv_in[node] = dg > 0 ? rsqrtf((float)dg) : 0.f;
    }
  }
  if (b == NB - 1 && t == 0) off[NSEQ] = ECON;
  for (int i = t; i < cnt; i += 256) {
    uint32 pk = bp[i];
    int dl = pk >> 17;
    int p = gbase + loff[dl] + atomicAdd(&cursor[dl], 1);
    esrc[p] = (int)(pk & 0x1FFFF);
  }
}

// ---------------- CSR build pass B (src): out-degree -> dinv_out --------------
__global__ __launch_bounds__(256) void k_binBS(const ushort* __restrict__ spair,
                                               const int* __restrict__ sbucket_cnt,
                                               float* __restrict__ dinv_out) {
  __shared__ int deg[BW];
  int b = blockIdx.x, t = threadIdx.x;
  int cnt = sbucket_cnt[b];
  deg[t] = 0; deg[t + 256] = 0;
  __syncthreads();
  const ushort* sp = &spair[(size_t)b * BCAP];
  for (int i = t; i < cnt; i += 256) atomicAdd(&deg[sp[i]], 1);
  __syncthreads();
  #pragma unroll
  for (int k = 0; k < 2; ++k) {
    int j = t + k * 256;
    int node = b * BW + j;
    if (node < NSEQ) {
      int dg = deg[j];
      dinv_out[node] = dg > 0 ? rsqrtf((float)dg) : 0.f;
    }
  }
}

// ---------------- label counting sort: row indices grouped by label -----------
__global__ __launch_bounds__(256) void k_lab_scatter(const int* __restrict__ lab,
                                                     int* lab_cursor,
                                                     int* __restrict__ lab_sorted) {
  __shared__ int hist[NLAB], base[NLAB];
  int t = threadIdx.x;
  if (t < NLAB) hist[t] = 0;
  __syncthreads();
  int r0 = blockIdx.x * RPB, r1 = min(r0 + RPB, NSEQ);
  for (int r = r0 + t; r < r1; r += 256) atomicAdd(&hist[lab[r]], 1);
  __syncthreads();
  if (t < NLAB) {
    int c = hist[t];
    base[t] = (c > 0) ? atomicAdd(&lab_cursor[t], c) : 0;
    hist[t] = 0;
  }
  __syncthreads();
  for (int r = r0 + t; r < r1; r += 256) {
    int l = lab[r];
    int p = base[l] + atomicAdd(&hist[l], 1);
    lab_sorted[p] = r;
  }
}

// ---------------- BN params: statsP -> a[], cc[] ------------------------------
__global__ __launch_bounds__(128) void k_bnparams(const float* __restrict__ statsP,
                                                  const float* __restrict__ g,
                                                  const float* __restrict__ beta,
                                                  float* __restrict__ aV,
                                                  float* __restrict__ ccV) {
  int c = threadIdx.x;   // 128
  float s = 0.f, q = 0.f;
  #pragma unroll
  for (int k = 0; k < NPART; ++k) {
    s += statsP[k * 256 + c];
    q += statsP[k * 256 + 128 + c];
  }
  const float invN = 1.f / (float)NSEQ;
  float m = s * invN;
  float a = rsqrtf(q * invN - m * m + BN_EPS) * g[c];
  aV[c] = a;
  ccV[c] = beta[c] - m * a;
}

// ---------------- label aggregation via sorted gather -------------------------
// AFFINE=1: source is pre-BN; output = a ⊙ Σpre + cnt*cc (BN folded in)
template <int AFFINE>
__global__ __launch_bounds__(256) void k_lab_agg(const uint32* __restrict__ xb,
                                                 const int* __restrict__ lab_sorted,
                                                 const int* __restrict__ lab_base,
                                                 const float* __restrict__ aV,
                                                 const float* __restrict__ ccV,
                                                 float* __restrict__ lab_agg) {
  __shared__ float accs[4][D];
  int t = threadIdx.x;
  int l = blockIdx.x >> 3, p = blockIdx.x & 7;
  int w = t >> 6, cp = t & 63;
  int i0 = lab_base[l], i1 = lab_base[l + 1];
  float ax = 0.f, ay = 0.f;
  for (int i = i0 + p * 4 + w; i < i1; i += 32) {
    int r = lab_sorted[i];
    uint32 u = xb[r * 64 + cp];
    ax += blo(u); ay += bhi(u);
  }
  accs[w][2 * cp] = ax;
  accs[w][2 * cp + 1] = ay;
  __syncthreads();
  if (w == 0) {
    float s0 = accs[0][2 * cp] + accs[1][2 * cp] + accs[2][2 * cp] + accs[3][2 * cp];
    float s1 = accs[0][2 * cp + 1] + accs[1][2 * cp + 1] + accs[2][2 * cp + 1] + accs[3][2 * cp + 1];
    if (AFFINE) {
      s0 *= aV[2 * cp];
      s1 *= aV[2 * cp + 1];
      if (p == 0) {
        float cnt = (float)(i1 - i0);
        s0 += cnt * ccV[2 * cp];
        s1 += cnt * ccV[2 * cp + 1];
      }
    }
    atomAddF(&lab_agg[l * D + 2 * cp], s0);
    atomAddF(&lab_agg[l * D + 2 * cp + 1], s1);
  }
}

// ---------------- fp32 -> bf16 cast (pure stream) ------------------------------
__global__ __launch_bounds__(256) void k_cast(const float* __restrict__ x,
                                              uint32* __restrict__ xb) {
  int i = blockIdx.x * 256 + threadIdx.x;     // float4 index
  if (i >= NSEQ * D / 4) return;
  float4 v = ((const float4*)x)[i];
  uint32 u0 = (uint32)f2b(v.x) | ((uint32)f2b(v.y) << 16);
  uint32 u1 = (uint32)f2b(v.z) | ((uint32)f2b(v.w) << 16);
  ((uint2*)xb)[i] = make_uint2(u0, u1);
}

// ---------------- weight prep: W (128x128 fp32, k-major) -> W^T bf16 ----------
__global__ __launch_bounds__(256) void k_prep_w(const float* __restrict__ W1,
                                                const float* __restrict__ W2,
                                                short* __restrict__ wT1,
                                                short* __restrict__ wT2) {
  int i = blockIdx.x * 256 + threadIdx.x;
  if (i < 16384) {
    int k = i >> 7, c = i & 127;
    wT1[c * 128 + k] = (short)f2b(W1[i]);
  } else if (i < 32768) {
    int j = i - 16384;
    int k = j >> 7, c = j & 127;
    wT2[c * 128 + k] = (short)f2b(W2[j]);
  }
}

// ---------------- small matmul: out[64][ncol] = op((A*rowscale) @ W + bias) ---
__global__ __launch_bounds__(256) void k_mm(
    const float* __restrict__ A, const float* __restrict__ rowscale,
    const float* __restrict__ W, const float* __restrict__ bias,
    float* __restrict__ out, int ncol, int relu) {
  __shared__ float sA[4 * D];
  int tid = threadIdx.x;
  int rows_pb = 256 / ncol;
  int row0 = blockIdx.x * rows_pb;
  int nload = rows_pb * D;
  for (int i = tid; i < nload; i += 256) {
    int r = row0 + (i >> 7);
    float s = rowscale ? rowscale[r] : 1.f;
    sA[i] = A[r * D + (i & 127)] * s;
  }
  __syncthreads();
  int j = tid & (ncol - 1);
  int r = tid / ncol;
  const float* a = &sA[r * D];
  const float* w = &W[j];
  float acc0 = 0.f, acc1 = 0.f, acc2 = 0.f, acc3 = 0.f;
  #pragma unroll 4
  for (int k = 0; k < D; k += 4) {
    acc0 = fmaf(a[k + 0], w[(k + 0) * ncol], acc0);
    acc1 = fmaf(a[k + 1], w[(k + 1) * ncol], acc1);
    acc2 = fmaf(a[k + 2], w[(k + 2) * ncol], acc2);
    acc3 = fmaf(a[k + 3], w[(k + 3) * ncol], acc3);
  }
  float s = (acc0 + acc1) + (acc2 + acc3);
  if (bias) s += bias[j];
  if (relu) s = fmaxf(s, 0.f);
  out[(row0 + r) * ncol + j] = s;
}

// ---------------- BN over 64 label rows ---------------------------------------
__global__ __launch_bounds__(256) void k_label_bn(
    const float* __restrict__ pre,
    const float* __restrict__ g, const float* __restrict__ beta,
    float* __restrict__ out, int ncol) {
  __shared__ float psum[256], psq[256];
  __shared__ float sa[128], sc[128];
  int tid = threadIdx.x;
  int ngrp = 256 / ncol;
  int grp = tid / ncol;
  int col = tid & (ncol - 1);
  float s = 0.f, q = 0.f;
  for (int r = grp; r < NLAB; r += ngrp) {
    float v = pre[r * ncol + col];
    s += v; q += v * v;
  }
  psum[tid] = s; psq[tid] = q;
  __syncthreads();
  if (tid < ncol) {
    float S = 0.f, Q = 0.f;
    for (int gi = 0; gi < ngrp; ++gi) { S += psum[gi * ncol + tid]; Q += psq[gi * ncol + tid]; }
    float m = S * (1.f / NLAB);
    float v = Q * (1.f / NLAB) - m * m;
    float a = rsqrtf(v + BN_EPS) * g[tid];
    sa[tid] = a; sc[tid] = beta[tid] - m * a;
  }
  __syncthreads();
  for (int i = tid; i < NLAB * ncol; i += 256) {
    int c = i & (ncol - 1);
    out[i] = pre[i] * sa[c] + sc[c];
  }
}

// ---------------- connected_to aggregation: bf16 in, bf16 out -----------------
// AFFINE=1: source is pre-BN h1; BN folded in via a,cc and edge-weight sum.
template <int AFFINE>
__global__ __launch_bounds__(256) void k_con_agg_bf(
    const uint32* __restrict__ xb, const int* __restrict__ esrc,
    const int* __restrict__ off,
    const float* __restrict__ dinv_out, const float* __restrict__ dinv_in,
    const float* __restrict__ aV, const float* __restrict__ ccV,
    uint32* __restrict__ outb) {
  int wid = (blockIdx.x * 256 + threadIdx.x) >> 6;   // dst node
  int lane = threadIdx.x & 63;
  if (wid >= NSEQ) return;
  int e0 = off[wid], e1 = off[wid + 1];
  float ax = 0.f, ay = 0.f, sw = 0.f;
  int e = e0;
  for (; e + 3 < e1; e += 4) {
    int s0 = esrc[e], s1 = esrc[e + 1], s2 = esrc[e + 2], s3 = esrc[e + 3];
    float w0 = dinv_out[s0], w1 = dinv_out[s1], w2 = dinv_out[s2], w3 = dinv_out[s3];
    uint32 u0 = xb[s0 * 64 + lane];
    uint32 u1 = xb[s1 * 64 + lane];
    uint32 u2 = xb[s2 * 64 + lane];
    uint32 u3 = xb[s3 * 64 + lane];
    ax += blo(u0) * w0 + blo(u1) * w1 + blo(u2) * w2 + blo(u3) * w3;
    ay += bhi(u0) * w0 + bhi(u1) * w1 + bhi(u2) * w2 + bhi(u3) * w3;
    if (AFFINE) sw += (w0 + w1) + (w2 + w3);
  }
  for (; e < e1; ++e) {
    int s0 = esrc[e];
    float w0 = dinv_out[s0];
    uint32 u0 = xb[s0 * 64 + lane];
    ax += blo(u0) * w0;
    ay += bhi(u0) * w0;
    if (AFFINE) sw += w0;
  }
  float di = dinv_in[wid];
  float rx, ry;
  if (AFFINE) {
    float a0 = aV[2 * lane], a1 = aV[2 * lane + 1];
    float c0 = ccV[2 * lane], c1 = ccV[2 * lane + 1];
    rx = di * fmaf(a0, ax, c0 * sw);
    ry = di * fmaf(a1, ay, c1 * sw);
  } else {
    rx = di * ax;
    ry = di * ay;
  }
  uint32 p = (uint32)f2b(rx) | ((uint32)f2b(ry) << 16);
  outb[wid * 64 + lane] = p;
}

// ---------------- MFMA GEMM + epilogue + BN partial stats ----------------------
template <int OUTBF>
__global__ __launch_bounds__(256) void k_gemm_mfma(
    const short* __restrict__ aggbf,    // NSEQ x 128 bf16
    const short* __restrict__ wT,       // 128(col) x 128(k) bf16
    const float* __restrict__ b_con,
    const float* __restrict__ y_inc,    // 64x128 fp32
    const float* __restrict__ b_inc,
    const float* __restrict__ dinv_cnt,
    const int* __restrict__ bel,
    float* __restrict__ outF,           // fp32 out (OUTBF=0)
    short* __restrict__ outB,           // bf16 out (OUTBF=1)
    float* __restrict__ statsP) {       // NPART x [sum 128][sumsq 128]
  __shared__ short sW[128 * 136];       // 272B row stride
  __shared__ float csum[D], csq[D];
  int t = threadIdx.x;
  {
    const uint4* src = (const uint4*)wT;   // 2048 uint4, 16 per row
    for (int i = t; i < 2048; i += 256) {
      int row = i >> 4, part = i & 15;
      *(uint4*)&sW[row * 136 + part * 8] = src[i];
    }
  }
  if (t < D) { csum[t] = 0.f; csq[t] = 0.f; }
  int w = t >> 6, l = t & 63;
  int lr = l & 15, lg = l >> 4;
  int row0 = blockIdx.x * 64 + w * 16;
  bf16x8 afrag[4];
  {
    int arow = min(row0 + lr, NSEQ - 1);
    const short* ab = aggbf + arow * 128 + lg * 8;
    #pragma unroll
    for (int kt = 0; kt < 4; ++kt)
      afrag[kt] = *(const bf16x8*)(ab + kt * 32);
  }
  __syncthreads();
  f32x4 acc[8];
  #pragma unroll
  for (int ct = 0; ct < 8; ++ct) {
    f32x4 a = {0.f, 0.f, 0.f, 0.f};
    const short* wb = &sW[(ct * 16 + lr) * 136 + lg * 8];
    #pragma unroll
    for (int kt = 0; kt < 4; ++kt) {
      bf16x8 bfr = *(const bf16x8*)(wb + kt * 32);
      a = __builtin_amdgcn_mfma_f32_16x16x32_bf16(afrag[kt], bfr, a, 0, 0, 0);
    }
    acc[ct] = a;
  }
  int belr[4]; float dcv[4]; int rowv[4];
  #pragma unroll
  for (int r = 0; r < 4; ++r) {
    int gr = row0 + lg * 4 + r;
    rowv[r] = gr;
    int cl = min(gr, NSEQ - 1);
    belr[r] = bel[cl];
    dcv[r] = dinv_cnt[belr[r]];
  }
  #pragma unroll
  for (int ct = 0; ct < 8; ++ct) {
    int col = ct * 16 + lr;
    float bc = b_con[col], bi = b_inc[col];
    float s = 0.f, q = 0.f;
    #pragma unroll
    for (int r = 0; r < 4; ++r) {
      if (rowv[r] < NSEQ) {
        float o = acc[ct][r] + bc + fmaf(dcv[r], y_inc[belr[r] * D + col], bi);
        o = fmaxf(0.5f * o, 0.f);
        if (OUTBF) outB[rowv[r] * D + col] = (short)f2b(o);
        else       outF[rowv[r] * D + col] = o;
        s += o; q += o * o;
      }
    }
    s += __shfl_xor(s, 16); s += __shfl_xor(s, 32);
    q += __shfl_xor(q, 16); q += __shfl_xor(q, 32);
    if (lg == 0) {
      atomicAdd(&csum[col], s);
      atomicAdd(&csq[col], q);
    }
  }
  __syncthreads();
  float* sp = statsP + (blockIdx.x & (NPART - 1)) * 256;
  if (t < D) {
    atomAddF(&sp[t], csum[t]);
    atomAddF(&sp[D + t], csq[t]);
  }
}

// ---------------- final BN apply (fp32 in place, precomputed params) ----------
__global__ __launch_bounds__(256) void k_bn_apply2(
    float* __restrict__ buf, const float* __restrict__ aV,
    const float* __restrict__ ccV) {
  int t = threadIdx.x;
  int w = t >> 6, cp = t & 63;
  float a0 = aV[2 * cp], a1 = aV[2 * cp + 1];
  float c0 = ccV[2 * cp], c1 = ccV[2 * cp + 1];
  for (int r = blockIdx.x * 4 + w; r < NSEQ; r += gridDim.x * 4) {
    float2 v = ((float2*)buf)[r * 64 + cp];
    v.x = fmaf(v.x, a0, c0);
    v.y = fmaf(v.y, a1, c1);
    ((float2*)buf)[r * 64 + cp] = v;
  }
}

// ---------------- launch ------------------------------------------------------
extern "C" void kernel_launch(void* const* d_in, const int* in_sizes, int n_in,
                              void* d_out, int out_size, void* d_ws, size_t ws_size,
                              hipStream_t stream) {
  const float* x_seq   = (const float*)d_in[0];
  const float* x_label = (const float*)d_in[1];
  const float* W1_bel  = (const float*)d_in[2];
  const float* b1_bel  = (const float*)d_in[3];
  const float* W1_inc  = (const float*)d_in[4];
  const float* b1_inc  = (const float*)d_in[5];
  const float* W1_con  = (const float*)d_in[6];
  const float* b1_con  = (const float*)d_in[7];
  const float* g1s     = (const float*)d_in[8];
  const float* beta1s  = (const float*)d_in[9];
  const float* g1l     = (const float*)d_in[10];
  const float* beta1l  = (const float*)d_in[11];
  const float* W2_bel  = (const float*)d_in[12];
  const float* b2_bel  = (const float*)d_in[13];
  const float* W2_inc  = (const float*)d_in[14];
  const float* b2_inc  = (const float*)d_in[15];
  const float* W2_con  = (const float*)d_in[16];
  const float* b2_con  = (const float*)d_in[17];
  const float* g2s     = (const float*)d_in[18];
  const float* beta2s  = (const float*)d_in[19];
  const float* g2l     = (const float*)d_in[20];
  const float* beta2l  = (const float*)d_in[21];
  const int* bel       = (const int*)d_in[22];
  const int* con_src   = (const int*)d_in[23];
  const int* con_dst   = (const int*)d_in[24];
  float* out = (float*)d_out;

  char* ws = (char*)d_ws;
  short*  aggbf    = (short*) (ws);                  // 25,600,000 B
  short*  h1pre    = (short*) (ws + 25600000);       // 25,600,000 B
  uint32* bpair    = (uint32*)(ws + 32000000);       //  8,028,160 B (dead after binB)
  ushort* spair    = (ushort*)(ws + 40028160);       //  4,014,080 B (dead after binBS)
  int*    esrc     = (int*)   (ws + 51200000);       //  6,400,000 B
  float*  dinv_out = (float*) (ws + 57600000);       //    400,000 B
  // ---- zeroed region start (134,144 B) ----
  int*    cnt_lab     = (int*)  (ws + 58000000);     //   1,024
  int*    bucket_cnt  = (int*)  (ws + 58001024);     //   1,024
  int*    sbucket_cnt = (int*)  (ws + 58002048);     //   1,024
  float*  statsP1     = (float*)(ws + 58003072);     //  32,768 (32 x 256 f32)
  float*  statsP2     = (float*)(ws + 58035840);     //  32,768
  float*  lab_agg1    = (float*)(ws + 58068608);     //  32,768
  float*  lab_agg2    = (float*)(ws + 58101376);     //  32,768
  // ---- zeroed region end (58,134,144) ----
  float*  dinv_in    = (float*)(ws + 58134144);      // 400,000
  float*  dinv_cnt   = (float*)(ws + 58534144);      //     256
  int*    bbase      = (int*)  (ws + 58534400);      //   1,024
  int*    off        = (int*)  (ws + 58535424);      // 400,128
  float*  y_inc1     = (float*)(ws + 58935552);      //  32,768
  float*  y_inc2     = (float*)(ws + 58968320);      //  32,768
  float*  h_l1       = (float*)(ws + 59001088);      //  32,768
  short*  wT1        = (short*)(ws + 59033856);      //  32,768
  short*  wT2        = (short*)(ws + 59066624);      //  32,768
  int*    lab_base   = (int*)  (ws + 59099392);      //   1,024 (65 used)
  int*    lab_cursor = (int*)  (ws + 59100416);      //   1,024
  int*    lab_sorted = (int*)  (ws + 59101440);      // 400,000
  float*  ab1        = (float*)(ws + 59501440);      //     512
  float*  cc1        = (float*)(ws + 59501952);      //     512
  float*  ab2        = (float*)(ws + 59502464);      //     512
  float*  cc2        = (float*)(ws + 59502976);      //     512
  // end: 59,503,488 B

  uint32* xb = (uint32*)out;           // bf16 x features, d_out[0..25.6MB)
  float* belp1 = (float*)ws;           // transient, overwritten by con_agg
  float* belp2 = (float*)ws;

  hipMemsetAsync(ws + 58000000, 0, 134144, stream);

  // CSR build (dual-key, atomic-free per edge) + label sort + prep
  k_label_hist <<<256, 256, 0, stream>>>(bel, cnt_lab);
  k_binA       <<<(ECON + EPB - 1) / EPB, 256, 0, stream>>>(con_src, con_dst,
                                                            bucket_cnt, sbucket_cnt,
                                                            bpair, spair);
  k_bscan      <<<1, 256, 0, stream>>>(bucket_cnt, bbase, cnt_lab, dinv_cnt,
                                       lab_base, lab_cursor);
  k_binB       <<<NB, 256, 0, stream>>>(bpair, bucket_cnt, bbase,
                                        off, dinv_in, esrc);
  k_binBS      <<<NB, 256, 0, stream>>>(spair, sbucket_cnt, dinv_out);
  k_lab_scatter<<<(NSEQ + RPB - 1) / RPB, 256, 0, stream>>>(bel, lab_cursor, lab_sorted);
  k_cast       <<<(NSEQ * D / 4 + 255) / 256, 256, 0, stream>>>(x_seq, xb);
  k_prep_w     <<<128, 256, 0, stream>>>(W1_con, W2_con, wT1, wT2);

  // ---- layer 1 ----
  k_lab_agg<0> <<<NLAB * 8, 256, 0, stream>>>(xb, lab_sorted, lab_base,
                                              nullptr, nullptr, lab_agg1);
  k_mm         <<<32, 256, 0, stream>>>(x_label, nullptr, W1_inc, nullptr, y_inc1, 128, 0);
  k_mm         <<<32, 256, 0, stream>>>(lab_agg1, dinv_cnt, W1_bel, b1_bel, belp1, 128, 1);
  k_label_bn   <<<1, 256, 0, stream>>>(belp1, g1l, beta1l, h_l1, 128);
  k_con_agg_bf<0><<<NSEQ / 4, 256, 0, stream>>>(xb, esrc, off, dinv_out, dinv_in,
                                                nullptr, nullptr, (uint32*)aggbf);
  k_gemm_mfma<1><<<(NSEQ + 63) / 64, 256, 0, stream>>>(
                   aggbf, wT1, b1_con, y_inc1, b1_inc, dinv_cnt, bel,
                   nullptr, h1pre, statsP1);
  k_bnparams   <<<1, 128, 0, stream>>>(statsP1, g1s, beta1s, ab1, cc1);

  // ---- layer 2 (BN folded into linear consumers; no bn-apply stream pass) ----
  k_lab_agg<1> <<<NLAB * 8, 256, 0, stream>>>((const uint32*)h1pre, lab_sorted,
                                              lab_base, ab1, cc1, lab_agg2);
  k_mm         <<<32, 256, 0, stream>>>(h_l1, nullptr, W2_inc, nullptr, y_inc2, 128, 0);
  k_mm         <<<16, 256, 0, stream>>>(lab_agg2, dinv_cnt, W2_bel, b2_bel, belp2, 64, 1);
  k_label_bn   <<<1, 256, 0, stream>>>(belp2, g2l, beta2l, out + (size_t)NSEQ * D, 64);
  k_con_agg_bf<1><<<NSEQ / 4, 256, 0, stream>>>((const uint32*)h1pre, esrc, off,
                                                dinv_out, dinv_in, ab1, cc1,
                                                (uint32*)aggbf);
  k_gemm_mfma<0><<<(NSEQ + 63) / 64, 256, 0, stream>>>(
                   aggbf, wT2, b2_con, y_inc2, b2_inc, dinv_cnt, bel,
                   out, nullptr, statsP2);
  k_bnparams   <<<1, 128, 0, stream>>>(statsP2, g2s, beta2s, ab2, cc2);
  k_bn_apply2  <<<1024, 256, 0, stream>>>(out, ab2, cc2);
}